// Round 6
// baseline (58.213 us; speedup 1.0000x reference)
//
#include <hip/hip_runtime.h>
#include <math.h>

// Problem constants (fixed by setup_inputs)
constexpr int kB = 32;         // batch
constexpr int kS = 128;        // seq len
constexpr int kD = 256;        // hidden
constexpr int kK = 8;          // window
constexpr int kNPair = 2104;   // pairs with |j-i|<=8
constexpr int kInDim = 576;    // 2D + P
constexpr int kRows = 4096;    // B*S

typedef __attribute__((ext_vector_type(8))) short short8;   // 8 bf16
typedef __attribute__((ext_vector_type(4))) float f32x4;    // MFMA C/D frag

// f32 -> bf16, round-to-nearest-even
__device__ inline ushort f2b(float f) {
  union { float f; uint u; } v; v.f = f;
  uint r = v.u + 0x7FFF + ((v.u >> 16) & 1);
  return (ushort)(r >> 16);
}

// ---------------------------------------------------------------------------
// prep: one-time conversions into workspace (all plain row-major, no swizzle).
//  blocks 0..255  : Hb[4096][256] bf16
//  blocks 256..287: Wb[512][256] bf16 (row c = output col; cols 0..255 -> W1a,
//                   256..511 -> W1b)
//  block 288      : Rg[17][256] f32 = Kpe @ W1c^T + b1
// ---------------------------------------------------------------------------
__global__ __launch_bounds__(256) void prep(
    const float* __restrict__ H, const float* __restrict__ pos_emb,
    const float* __restrict__ W1, const float* __restrict__ b1,
    ushort* __restrict__ Hb, ushort* __restrict__ Wb, float* __restrict__ Rg) {
  const int blk = blockIdx.x, tid = threadIdx.x;
  if (blk < 256) {
#pragma unroll
    for (int l = 0; l < 4; ++l) {
      int c = blk * 1024 + l * 256 + tid;      // [0, 262144) float4-chunks
      float4 a = *(const float4*)(H + c * 4);
      ushort4 u; u.x = f2b(a.x); u.y = f2b(a.y); u.z = f2b(a.z); u.w = f2b(a.w);
      *(ushort4*)(Hb + c * 4) = u;
    }
  } else if (blk < 288) {
    int bb = blk - 256;
#pragma unroll
    for (int l = 0; l < 4; ++l) {
      int c = bb * 1024 + l * 256 + tid;       // [0, 32768) float4-chunks
      int r = c >> 6;                          // output col 0..511
      int kq = (c & 63) << 2;
      const float* src = W1 + (r & 255) * kInDim + ((r < 256) ? 0 : 256) + kq;
      float4 a = *(const float4*)src;
      ushort4 u; u.x = f2b(a.x); u.y = f2b(a.y); u.z = f2b(a.z); u.w = f2b(a.w);
      *(ushort4*)(Wb + r * 256 + kq) = u;
    }
  } else {
    // R[t][d] = sum_u (128-|u-8|)*exp(-(t-u)^2)*(pos_emb[u].W1c[d]) + b1[d]
    __shared__ float pe[17 * 64];
    for (int idx = tid; idx < 17 * 64; idx += 256) pe[idx] = pos_emb[idx];
    __syncthreads();
    const int d = tid;
    float w[64];
    const float* wr = W1 + d * kInDim + 512;
#pragma unroll
    for (int q = 0; q < 16; ++q) {
      float4 t4 = *(const float4*)(wr + q * 4);
      w[q * 4 + 0] = t4.x; w[q * 4 + 1] = t4.y;
      w[q * 4 + 2] = t4.z; w[q * 4 + 3] = t4.w;
    }
    float acc[17];
#pragma unroll
    for (int t = 0; t < 17; ++t) acc[t] = 0.f;
    for (int u = 0; u < 17; ++u) {
      float m = 0.f;
#pragma unroll
      for (int p = 0; p < 64; ++p) m += pe[u * 64 + p] * w[p];
      int au = u - kK; if (au < 0) au = -au;
      m *= (float)(kS - au);
#pragma unroll
      for (int t = 0; t < 17; ++t) {
        int dd = t - u;
        acc[t] += expf((float)(-(dd * dd))) * m;
      }
    }
#pragma unroll
    for (int t = 0; t < 17; ++t) Rg[t * kD + d] = acc[t] + b1[d];
  }
}

// ---------------------------------------------------------------------------
// gemm_tiles: one wave per 16x16 output tile of C[4096][512] = Hb x Wb^T.
// No LDS, no barriers: each lane loads its MFMA fragments straight from
// global (L2-resident bf16 images), 8 MFMAs in 2 independent chains, store.
// 8192 waves -> ~6-8 waves/SIMD of pure TLP latency hiding.
// ---------------------------------------------------------------------------
__global__ __launch_bounds__(256) void gemm_tiles(
    const ushort* __restrict__ Hb, const ushort* __restrict__ Wb,
    float* __restrict__ U, float* __restrict__ V) {
  const int tid = threadIdx.x;
  const int lane = tid & 63;
  const int gw = blockIdx.x * 4 + (tid >> 6);   // 0..8191
  const int m = gw & 255;                       // M strip (block's 4 waves: same n, m+0..3)
  const int n = gw >> 8;                        // 0..31 -> B-frag shared in-block via L1
  const int lr = lane & 15;
  const int lk = (lane >> 4) << 3;
  const ushort* Arow = Hb + (m * 16 + lr) * 256 + lk;
  const ushort* Brow = Wb + (n * 16 + lr) * 256 + lk;
  short8 a[8], bb[8];
#pragma unroll
  for (int kk = 0; kk < 8; ++kk) {
    a[kk]  = *(const short8*)(const void*)(Arow + kk * 32);
    bb[kk] = *(const short8*)(const void*)(Brow + kk * 32);
  }
  f32x4 acc0 = {0.f, 0.f, 0.f, 0.f}, acc1 = {0.f, 0.f, 0.f, 0.f};
#pragma unroll
  for (int kk = 0; kk < 8; kk += 2) {
    acc0 = __builtin_amdgcn_mfma_f32_16x16x32_bf16(a[kk],     bb[kk],     acc0, 0, 0, 0);
    acc1 = __builtin_amdgcn_mfma_f32_16x16x32_bf16(a[kk + 1], bb[kk + 1], acc1, 0, 0, 0);
  }
  // C/D mapping: col = lane&15 (output col), row = (lane>>4)*4 + reg (output row)
  const int cg = n * 16 + lr;
  float* dst = (cg < kD) ? (U + cg) : (V + (cg - kD));
  const int rowbase = m * 16 + ((lane >> 4) << 2);
#pragma unroll
  for (int r = 0; r < 4; ++r)
    dst[(rowbase + r) * kD] = acc0[r] + acc1[r];
}

// ---------------------------------------------------------------------------
// pair_score2: one 16-lane group per pair (4 pairs/wave), all-global reads.
// h = U[b,i]+V[b,j]+R[rel]; LayerNorm (fused sum+sumsq); ELU; dot W2.
// ---------------------------------------------------------------------------
__global__ __launch_bounds__(256) void pair_score2(
    const float* __restrict__ U, const float* __restrict__ V,
    const float* __restrict__ R,
    const float* __restrict__ ln_g, const float* __restrict__ ln_b,
    const float* __restrict__ W2, const float* __restrict__ b2,
    float* __restrict__ out) {
  const int tid = threadIdx.x;
  const int l16 = tid & 15;
  const int grp = (blockIdx.x * 256 + tid) >> 4;   // 16-lane group id
  const int t = grp % 17;                          // rel + 8
  const int bi = grp / 17;
  const int i = bi & (kS - 1);
  const int b = bi >> 7;                           // 0..31 by construction
  const int j = i - kK + t;
  const bool valid = (j >= 0) && (j < kS);
  const int jc = valid ? j : 0;

  // closed-form pair index p
  int start_i;
  if (i <= 8)        start_i = (i * i + 17 * i) / 2;
  else if (i <= 120) start_i = 100 + (i - 8) * 17;
  else { int m = i - 120; start_i = 2004 + 16 * m - (m * (m - 1)) / 2; }
  const int lower = (i - kK > 0) ? (i - kK) : 0;
  const int p = start_i + (j - lower);

  const float* Urow = U + (b * kS + i) * kD;
  const float* Vrow = V + (b * kS + jc) * kD;
  const float* Rrow = R + t * kD;

  float h[16];
  float s = 0.f, qs = 0.f;
#pragma unroll
  for (int q = 0; q < 4; ++q) {
    const int d = q * 64 + l16 * 4;
    float4 u4 = *(const float4*)(Urow + d);
    float4 v4 = *(const float4*)(Vrow + d);
    float4 r4 = *(const float4*)(Rrow + d);
    float h0 = u4.x + v4.x + r4.x;
    float h1 = u4.y + v4.y + r4.y;
    float h2 = u4.z + v4.z + r4.z;
    float h3 = u4.w + v4.w + r4.w;
    h[q * 4 + 0] = h0; h[q * 4 + 1] = h1; h[q * 4 + 2] = h2; h[q * 4 + 3] = h3;
    s += h0 + h1 + h2 + h3;
    qs += h0 * h0 + h1 * h1 + h2 * h2 + h3 * h3;
  }
#pragma unroll
  for (int off = 8; off > 0; off >>= 1) {
    s  += __shfl_xor(s, off);
    qs += __shfl_xor(qs, off);
  }
  const float mu = s * (1.0f / kD);
  const float var = qs * (1.0f / kD) - mu * mu;
  const float rs = rsqrtf(var + 1e-5f);

  float dot = 0.f;
#pragma unroll
  for (int q = 0; q < 4; ++q) {
    const int d = q * 64 + l16 * 4;
    float4 g4  = *(const float4*)(ln_g + d);
    float4 be4 = *(const float4*)(ln_b + d);
    float4 w4  = *(const float4*)(W2 + d);
    float y0 = (h[q * 4 + 0] - mu) * rs * g4.x + be4.x;
    float y1 = (h[q * 4 + 1] - mu) * rs * g4.y + be4.y;
    float y2 = (h[q * 4 + 2] - mu) * rs * g4.z + be4.z;
    float y3 = (h[q * 4 + 3] - mu) * rs * g4.w + be4.w;
    y0 = y0 > 0.f ? y0 : (__expf(y0) - 1.0f);   // elu (alpha=1), hw exp
    y1 = y1 > 0.f ? y1 : (__expf(y1) - 1.0f);
    y2 = y2 > 0.f ? y2 : (__expf(y2) - 1.0f);
    y3 = y3 > 0.f ? y3 : (__expf(y3) - 1.0f);
    dot += y0 * w4.x + y1 * w4.y + y2 * w4.z + y3 * w4.w;
  }
#pragma unroll
  for (int off = 8; off > 0; off >>= 1) dot += __shfl_xor(dot, off);

  if (l16 == 0 && valid) {
    out[b * kNPair + p] = dot + b2[0];
    if (b == 0) {
      float* posout = out + kB * kNPair;   // positions read back as f32
      posout[p * 2 + 0] = (float)(i + 1);
      posout[p * 2 + 1] = (float)(j + 1);
    }
  }
}

// ---------------------------------------------------------------------------
extern "C" void kernel_launch(void* const* d_in, const int* in_sizes, int n_in,
                              void* d_out, int out_size, void* d_ws, size_t ws_size,
                              hipStream_t stream) {
  (void)in_sizes; (void)n_in; (void)ws_size; (void)out_size;
  const float* H       = (const float*)d_in[0];  // [32,128,256]
  const float* pos_emb = (const float*)d_in[1];  // [17,64]
  const float* W1      = (const float*)d_in[2];  // [256,576]
  const float* b1      = (const float*)d_in[3];  // [256]
  const float* ln_g    = (const float*)d_in[4];  // [256]
  const float* ln_b    = (const float*)d_in[5];  // [256]
  const float* W2      = (const float*)d_in[6];  // [1,256]
  const float* b2      = (const float*)d_in[7];  // [1]
  float* out = (float*)d_out;

  ushort* Hb = (ushort*)d_ws;                 // [4096][256] bf16
  ushort* Wb = Hb + kRows * kD;               // [512][256] bf16
  float*  Rg = (float*)(Wb + 512 * kD);       // [17][256] f32
  float*  U  = Rg + 17 * kD;                  // [4096][256] f32
  float*  V  = U + kRows * kD;                // [4096][256] f32

  prep<<<289, 256, 0, stream>>>(H, pos_emb, W1, b1, Hb, Wb, Rg);
  gemm_tiles<<<2048, 256, 0, stream>>>(Hb, Wb, U, V);
  const int n_groups = kB * kS * 17;          // 69632 pair-slots, 16 per block
  pair_score2<<<n_groups / 16, 256, 0, stream>>>(U, V, Rg, ln_g, ln_b, W2, b2, out);
}

// Round 7
// 53.292 us; speedup vs baseline: 1.0923x; 1.0923x over previous
//
#include <hip/hip_runtime.h>
#include <hip/hip_bf16.h>
#include <math.h>

// Problem constants (fixed by setup_inputs)
constexpr int kB = 32;         // batch
constexpr int kS = 128;        // seq len
constexpr int kD = 256;        // hidden
constexpr int kK = 8;          // window
constexpr int kNPair = 2104;   // pairs with |j-i|<=8
constexpr int kInDim = 576;    // 2D + P
constexpr int kRS = 260;       // padded f32 LDS row stride: mult of 4 (b128 align),
                               // 4*260 % 32 == 16 -> C-write quarters 2-way (free)

typedef __attribute__((ext_vector_type(8))) short short8;   // 8 bf16
typedef __attribute__((ext_vector_type(4))) float f32x4;    // MFMA C/D frag

// pack 8 f32 -> 8 bf16 (RNE) via v_cvt_pk_bf16_f32
__device__ inline short8 pack8(float4 p, float4 q) {
  union { short8 s; __hip_bfloat162 h[4]; } u;
  u.h[0] = __float22bfloat162_rn(make_float2(p.x, p.y));
  u.h[1] = __float22bfloat162_rn(make_float2(p.z, p.w));
  u.h[2] = __float22bfloat162_rn(make_float2(q.x, q.y));
  u.h[3] = __float22bfloat162_rn(make_float2(q.z, q.w));
  return u.s;
}

// ---------------------------------------------------------------------------
// Single fused kernel. Block = (batch b, 16-row i-chunk); 1024 threads =
// 16 waves = 4 waves/SIMD. ONE barrier total.
//   waves 0-3  : R[17][256] -> sR (scalar pos_emb loads, const-folded exp)
//   waves 4-7  : stage ln_g/ln_b/W2 -> LDS
//   all 16     : GEMM C[32][512] = H_window x Wcat^T, frags direct from
//                global f32 with in-register cvt_pk->bf16, 4 tiles/wave,
//                results ds_write to sU/sV
//   barrier
//   all        : pair phase (64 groups x 16 lanes, 4-5 slots each)
// ---------------------------------------------------------------------------
__global__ __launch_bounds__(1024, 4) void fused(
    const float* __restrict__ H, const float* __restrict__ pos_emb,
    const float* __restrict__ W1, const float* __restrict__ b1,
    const float* __restrict__ ln_g, const float* __restrict__ ln_b,
    const float* __restrict__ W2, const float* __restrict__ b2,
    float* __restrict__ out) {
  __shared__ float sU[16 * kRS];    // 16.3 KB
  __shared__ float sV[32 * kRS];    // 32.5 KB
  __shared__ float sR[17 * kRS];    // 17.3 KB
  __shared__ float sG[256], sBe[256], sWo[256];

  const int tid = threadIdx.x;
  const int b = blockIdx.x >> 3;
  const int i0 = (blockIdx.x & 7) << 4;
  int ws_ = i0 - 8; if (ws_ < 0) ws_ = 0; if (ws_ > 96) ws_ = 96;
  const int ws = ws_;               // 32-row window start; covers U & V needs
  const int oi = i0 - ws;           // i-chunk offset in window (0, 8, or 16)

  if (tid >= 256 && tid < 512) {
    int t2 = tid - 256;
    sG[t2] = ln_g[t2]; sBe[t2] = ln_b[t2]; sWo[t2] = W2[t2];
  }
  if (tid < 256) {
    // R[t][d] = sum_u (128-|u-8|)*exp(-(t-u)^2)*(pos_emb[u].W1c[d]) + b1[d]
    const int d = tid;
    float w[64];
    const float* wr = W1 + d * kInDim + 512;
#pragma unroll
    for (int q = 0; q < 16; ++q) {
      float4 t4 = *(const float4*)(wr + q * 4);
      w[q * 4 + 0] = t4.x; w[q * 4 + 1] = t4.y;
      w[q * 4 + 2] = t4.z; w[q * 4 + 3] = t4.w;
    }
    float m[17];
#pragma unroll
    for (int u = 0; u < 17; ++u) {
      float s = 0.f;
#pragma unroll
      for (int p = 0; p < 16; ++p) {
        float4 pe = *(const float4*)(pos_emb + u * 64 + p * 4);  // lane-uniform
        s += pe.x * w[p * 4] + pe.y * w[p * 4 + 1] + pe.z * w[p * 4 + 2] + pe.w * w[p * 4 + 3];
      }
      int au = u - kK; if (au < 0) au = -au;
      m[u] = s * (float)(kS - au);
    }
#pragma unroll
    for (int t = 0; t < 17; ++t) {
      float a = 0.f;
#pragma unroll
      for (int u = 0; u < 17; ++u) {
        float e = __expf((float)(-(t - u) * (t - u)));  // const-folded
        a += e * m[u];
      }
      sR[t * kRS + d] = a + b1[d];
    }
  }

  // ---- GEMM: wave wv -> row-tile rt = wv&1, col-tiles (wv>>1)*4 + 0..3 ----
  const int lane = tid & 63;
  const int wv = tid >> 6;
  const int lr = lane & 15;
  const int lk = (lane >> 4) << 3;
  const int rt = wv & 1;
  {
    const float* Arow = H + (b * kS + ws + rt * 16 + lr) * kD + lk;
    short8 a[8];
#pragma unroll
    for (int kk = 0; kk < 8; ++kk) {
      float4 p = *(const float4*)(Arow + kk * 32);
      float4 q = *(const float4*)(Arow + kk * 32 + 4);
      a[kk] = pack8(p, q);
    }
#pragma unroll
    for (int ci = 0; ci < 4; ++ci) {
      const int ct = (wv >> 1) * 4 + ci;
      const int c = ct * 16 + lr;           // output col 0..511
      const float* Brow = W1 + (c & 255) * kInDim + ((c < 256) ? 0 : 256) + lk;
      f32x4 acc0 = {0.f, 0.f, 0.f, 0.f}, acc1 = {0.f, 0.f, 0.f, 0.f};
#pragma unroll
      for (int kk = 0; kk < 8; kk += 2) {
        float4 p0 = *(const float4*)(Brow + kk * 32);
        float4 q0 = *(const float4*)(Brow + kk * 32 + 4);
        short8 bf0 = pack8(p0, q0);
        acc0 = __builtin_amdgcn_mfma_f32_16x16x32_bf16(a[kk], bf0, acc0, 0, 0, 0);
        float4 p1 = *(const float4*)(Brow + (kk + 1) * 32);
        float4 q1 = *(const float4*)(Brow + (kk + 1) * 32 + 4);
        short8 bf1 = pack8(p1, q1);
        acc1 = __builtin_amdgcn_mfma_f32_16x16x32_bf16(a[kk + 1], bf1, acc1, 0, 0, 0);
      }
      // C/D map: col = lane&15 (== lr, matches B row), row = (lane>>4)*4 + r
      const int rb = rt * 16 + ((lane >> 4) << 2);
#pragma unroll
      for (int r = 0; r < 4; ++r) {
        float val = acc0[r] + acc1[r];
        int wr2 = rb + r;                   // window row 0..31
        if (c < 256) {
          unsigned ur = (unsigned)(wr2 - oi);
          if (ur < 16u) sU[ur * kRS + c] = val;
        } else {
          sV[wr2 * kRS + (c - 256)] = val;
        }
      }
    }
  }
  __syncthreads();

  // ---- pair phase: 64 groups x 16 lanes; group g: ir = g>>2, quarter q = g&3 ----
  const int g = tid >> 4, l16 = tid & 15;
  const int ir = g >> 2, qq = g & 3;
  const int tb = qq * 4 + (qq > 0);         // 0,5,9,13
  const int te = qq * 4 + 5;                // 5,9,13,17
  const int i = i0 + ir;

  float ureg[16];
#pragma unroll
  for (int q = 0; q < 4; ++q) {
    float4 u4 = *(const float4*)&sU[ir * kRS + (q << 6) + (l16 << 2)];
    ureg[q * 4 + 0] = u4.x; ureg[q * 4 + 1] = u4.y;
    ureg[q * 4 + 2] = u4.z; ureg[q * 4 + 3] = u4.w;
  }
  float4 Gp[4], Bp[4], Wp[4];
#pragma unroll
  for (int q = 0; q < 4; ++q) {
    int d = (q << 6) + (l16 << 2);
    Gp[q] = *(const float4*)&sG[d];
    Bp[q] = *(const float4*)&sBe[d];
    Wp[q] = *(const float4*)&sWo[d];
  }
  const float bias2 = b2[0];

  int start_i;
  if (i <= 8)        start_i = (i * i + 17 * i) / 2;
  else if (i <= 120) start_i = 100 + (i - 8) * 17;
  else { int mm = i - 120; start_i = 2004 + 16 * mm - (mm * (mm - 1)) / 2; }
  const int lower = (i - kK > 0) ? (i - kK) : 0;

  for (int t = tb; t < te; ++t) {
    int j = i - kK + t;
    if (j < 0 || j >= kS) continue;         // group-uniform
    const int p = start_i + (j - lower);
    const float* Vr = &sV[(j - ws) * kRS];
    const float* Rr = &sR[t * kRS];

    float h[16]; float ssum = 0.f, qsum = 0.f;
#pragma unroll
    for (int q = 0; q < 4; ++q) {
      int d = (q << 6) + (l16 << 2);
      float4 v4 = *(const float4*)(Vr + d);
      float4 r4 = *(const float4*)(Rr + d);
      float h0 = ureg[q * 4 + 0] + v4.x + r4.x;
      float h1 = ureg[q * 4 + 1] + v4.y + r4.y;
      float h2 = ureg[q * 4 + 2] + v4.z + r4.z;
      float h3 = ureg[q * 4 + 3] + v4.w + r4.w;
      h[q * 4 + 0] = h0; h[q * 4 + 1] = h1; h[q * 4 + 2] = h2; h[q * 4 + 3] = h3;
      ssum += h0 + h1 + h2 + h3;
      qsum += h0 * h0 + h1 * h1 + h2 * h2 + h3 * h3;
    }
#pragma unroll
    for (int off = 8; off > 0; off >>= 1) {
      ssum += __shfl_xor(ssum, off);
      qsum += __shfl_xor(qsum, off);
    }
    const float mu = ssum * (1.0f / kD);
    const float var = qsum * (1.0f / kD) - mu * mu;
    const float rs = rsqrtf(var + 1e-5f);
    float dot = 0.f;
#pragma unroll
    for (int q = 0; q < 4; ++q) {
      float y0 = (h[q * 4 + 0] - mu) * rs * Gp[q].x + Bp[q].x;
      float y1 = (h[q * 4 + 1] - mu) * rs * Gp[q].y + Bp[q].y;
      float y2 = (h[q * 4 + 2] - mu) * rs * Gp[q].z + Bp[q].z;
      float y3 = (h[q * 4 + 3] - mu) * rs * Gp[q].w + Bp[q].w;
      y0 = y0 > 0.f ? y0 : (__expf(y0) - 1.0f);   // elu (alpha=1)
      y1 = y1 > 0.f ? y1 : (__expf(y1) - 1.0f);
      y2 = y2 > 0.f ? y2 : (__expf(y2) - 1.0f);
      y3 = y3 > 0.f ? y3 : (__expf(y3) - 1.0f);
      dot += y0 * Wp[q].x + y1 * Wp[q].y + y2 * Wp[q].z + y3 * Wp[q].w;
    }
#pragma unroll
    for (int off = 8; off > 0; off >>= 1) dot += __shfl_xor(dot, off);

    if (l16 == 0) {
      out[b * kNPair + p] = dot + bias2;
      if (b == 0) {
        float* po = out + kB * kNPair;      // positions read back as f32
        po[2 * p + 0] = (float)(i + 1);
        po[2 * p + 1] = (float)(j + 1);
      }
    }
  }
}

// ---------------------------------------------------------------------------
extern "C" void kernel_launch(void* const* d_in, const int* in_sizes, int n_in,
                              void* d_out, int out_size, void* d_ws, size_t ws_size,
                              hipStream_t stream) {
  (void)in_sizes; (void)n_in; (void)d_ws; (void)ws_size; (void)out_size;
  const float* H       = (const float*)d_in[0];  // [32,128,256]
  const float* pos_emb = (const float*)d_in[1];  // [17,64]
  const float* W1      = (const float*)d_in[2];  // [256,576]
  const float* b1      = (const float*)d_in[3];  // [256]
  const float* ln_g    = (const float*)d_in[4];  // [256]
  const float* ln_b    = (const float*)d_in[5];  // [256]
  const float* W2      = (const float*)d_in[6];  // [1,256]
  const float* b2      = (const float*)d_in[7];  // [1]
  float* out = (float*)d_out;

  fused<<<kB * 8, 1024, 0, stream>>>(H, pos_emb, W1, b1, ln_g, ln_b, W2, b2, out);
}

// Round 8
// 52.832 us; speedup vs baseline: 1.1019x; 1.0087x over previous
//
#include <hip/hip_runtime.h>
#include <hip/hip_bf16.h>
#include <math.h>

// Problem constants (fixed by setup_inputs)
constexpr int kB = 32;         // batch
constexpr int kS = 128;        // seq len
constexpr int kD = 256;        // hidden
constexpr int kK = 8;          // window
constexpr int kNPair = 2104;   // pairs with |j-i|<=8
constexpr int kInDim = 576;    // 2D + P
constexpr int kRows = 4096;    // B*S
constexpr int kAP = 260;       // padded A-row stride in f32 (2-way max on ds_read_b128)

typedef __attribute__((ext_vector_type(8))) short short8;   // 8 bf16
typedef __attribute__((ext_vector_type(4))) float f32x4;    // MFMA C/D frag
typedef unsigned int u32;

// pack 8 f32 -> 8 bf16 (RNE) via v_cvt_pk_bf16_f32
__device__ inline short8 pack8(float4 p, float4 q) {
  union { short8 s; __hip_bfloat162 h[4]; } u;
  u.h[0] = __float22bfloat162_rn(make_float2(p.x, p.y));
  u.h[1] = __float22bfloat162_rn(make_float2(p.z, p.w));
  u.h[2] = __float22bfloat162_rn(make_float2(q.x, q.y));
  u.h[3] = __float22bfloat162_rn(make_float2(q.z, q.w));
  return u.s;
}

// async global->LDS DMA: 16 B per lane; gptr is per-lane, lds base wave-uniform
__device__ inline void gload16(const void* g, void* lds) {
  __builtin_amdgcn_global_load_lds(
      (const u32 __attribute__((address_space(1)))*)g,
      (u32 __attribute__((address_space(3)))*)lds, 16, 0, 0);
}

// ---------------------------------------------------------------------------
// G: blocks 0..511 compute C[4096][512] = H x Wcat^T -> U,V (f32).
//   block = (colgroup = blk&7 -> 4 col-tiles, one per wave; mgroup = blk>>3
//   -> 4 m-tiles of 16 rows). B-fragments persistent in registers (loaded
//   once); A-panels DMA'd into double-buffered LDS, conflict-free reads.
// block 512 computes Rg[17][256] = Kpe @ W1c^T + b1.
// ---------------------------------------------------------------------------
__global__ __launch_bounds__(256, 4) void gemm_uv(
    const float* __restrict__ H, const float* __restrict__ W1,
    const float* __restrict__ pos_emb, const float* __restrict__ b1,
    float* __restrict__ U, float* __restrict__ V, float* __restrict__ Rg) {
  const int tid = threadIdx.x;
  if (blockIdx.x == 512) {
    // ---- build_R: R[t][d] = sum_u (128-|u-8|)*exp(-(t-u)^2)*(pe[u].W1c[d]) + b1[d]
    __shared__ float pe[17 * 64];
    for (int idx = tid; idx < 17 * 64; idx += 256) pe[idx] = pos_emb[idx];
    __syncthreads();
    const int d = tid;
    float w[64];
    const float* wr = W1 + d * kInDim + 512;
#pragma unroll
    for (int q = 0; q < 16; ++q) {
      float4 t4 = *(const float4*)(wr + q * 4);
      w[q * 4 + 0] = t4.x; w[q * 4 + 1] = t4.y;
      w[q * 4 + 2] = t4.z; w[q * 4 + 3] = t4.w;
    }
    float acc[17];
#pragma unroll
    for (int t = 0; t < 17; ++t) acc[t] = 0.f;
    for (int u = 0; u < 17; ++u) {
      float m = 0.f;
#pragma unroll
      for (int p = 0; p < 64; ++p) m += pe[u * 64 + p] * w[p];
      int au = u - kK; if (au < 0) au = -au;
      m *= (float)(kS - au);
#pragma unroll
      for (int t = 0; t < 17; ++t) {
        int dd = t - u;
        acc[t] += expf((float)(-(dd * dd))) * m;
      }
    }
#pragma unroll
    for (int t = 0; t < 17; ++t) Rg[t * kD + d] = acc[t] + b1[d];
    return;
  }

  __shared__ __align__(16) float sA[2][16 * kAP];   // 2 x 16.6 KB
  const int lane = tid & 63;
  const int wv = tid >> 6;            // wave 0..3 -> col-tile
  const int lr = lane & 15;
  const int lk = (lane >> 4) << 3;    // k-slice start (floats)
  const int ct = (blockIdx.x & 7) * 4 + wv;   // col-tile 0..31
  const int c = ct * 16 + lr;                 // output col 0..511
  const int m0 = (int)(blockIdx.x >> 3) * 64; // 4 m-tiles of 16

  // ---- B fragments: persistent in registers, loaded once ----
  const float* Brow = W1 + (c & 255) * kInDim + ((c < 256) ? 0 : 256) + lk;
  short8 bf[8];
#pragma unroll
  for (int kk = 0; kk < 8; ++kk) {
    float4 p = *(const float4*)(Brow + kk * 32);
    float4 q = *(const float4*)(Brow + kk * 32 + 4);
    bf[kk] = pack8(p, q);
  }

  // ---- prologue: DMA m-tile 0 (each wave 4 rows, coalesced 1 KB/instr) ----
  for (int r = wv; r < 16; r += 4)
    gload16(H + (m0 + r) * kD + lane * 4, &sA[0][r * kAP]);
  __syncthreads();

  float* dst = (c < kD) ? (U + c) : (V + (c - kD));
  for (int mt = 0; mt < 4; ++mt) {
    const int cur = mt & 1;
    if (mt < 3) {                      // issue next A-panel DMA (drained at barrier)
      const int mb = m0 + (mt + 1) * 16;
      for (int r = wv; r < 16; r += 4)
        gload16(H + (mb + r) * kD + lane * 4, &sA[cur ^ 1][r * kAP]);
    }
    f32x4 acc0 = {0.f, 0.f, 0.f, 0.f}, acc1 = {0.f, 0.f, 0.f, 0.f};
#pragma unroll
    for (int kk = 0; kk < 8; kk += 2) {
      const float* ap0 = &sA[cur][lr * kAP + kk * 32 + lk];
      float4 p = *(const float4*)ap0; float4 q = *(const float4*)(ap0 + 4);
      acc0 = __builtin_amdgcn_mfma_f32_16x16x32_bf16(pack8(p, q), bf[kk], acc0, 0, 0, 0);
      const float* ap1 = &sA[cur][lr * kAP + (kk + 1) * 32 + lk];
      p = *(const float4*)ap1; q = *(const float4*)(ap1 + 4);
      acc1 = __builtin_amdgcn_mfma_f32_16x16x32_bf16(pack8(p, q), bf[kk + 1], acc1, 0, 0, 0);
    }
    // C/D map: col = lane&15 (== B row c), row = (lane>>4)*4 + r
    const int rowb = m0 + mt * 16 + ((lane >> 4) << 2);
#pragma unroll
    for (int r = 0; r < 4; ++r)
      dst[(rowb + r) * kD] = acc0[r] + acc1[r];
    __syncthreads();                   // readers done with cur^1, DMA drained
  }
}

// ---------------------------------------------------------------------------
// P: pair scores. No LDS, no barriers. Block = (b = blk>>4, 8-row i-chunk
// i0 = (blk&15)*8); 512 threads = 32 groups of 16 lanes; group g: i-row
// ir = g>>2, t-quarter qq = g&3 (4-5 slots). V window (24 rows) is L1-hot.
// ---------------------------------------------------------------------------
__global__ __launch_bounds__(512, 4) void pair_score(
    const float* __restrict__ U, const float* __restrict__ V,
    const float* __restrict__ R,
    const float* __restrict__ ln_g, const float* __restrict__ ln_b,
    const float* __restrict__ W2, const float* __restrict__ b2,
    float* __restrict__ out) {
  const int tid = threadIdx.x;
  const int l16 = tid & 15;
  const int g = tid >> 4;
  const int b = blockIdx.x >> 4;
  const int i0 = (blockIdx.x & 15) << 3;
  const int ir = g >> 2, qq = g & 3;
  const int tb = qq * 4 + (qq > 0);     // 0,5,9,13
  const int te = qq * 4 + 5;            // 5,9,13,17
  const int i = i0 + ir;

  float ureg[16];
  const float* Urow = U + (b * kS + i) * kD;
#pragma unroll
  for (int q = 0; q < 4; ++q) {
    float4 u4 = *(const float4*)(Urow + (q << 6) + (l16 << 2));
    ureg[q * 4 + 0] = u4.x; ureg[q * 4 + 1] = u4.y;
    ureg[q * 4 + 2] = u4.z; ureg[q * 4 + 3] = u4.w;
  }
  float4 Gp[4], Bp[4], Wp[4];
#pragma unroll
  for (int q = 0; q < 4; ++q) {
    int d = (q << 6) + (l16 << 2);
    Gp[q] = *(const float4*)(ln_g + d);
    Bp[q] = *(const float4*)(ln_b + d);
    Wp[q] = *(const float4*)(W2 + d);
  }
  const float bias2 = b2[0];

  int start_i;
  if (i <= 8)        start_i = (i * i + 17 * i) / 2;
  else if (i <= 120) start_i = 100 + (i - 8) * 17;
  else { int mm = i - 120; start_i = 2004 + 16 * mm - (mm * (mm - 1)) / 2; }
  const int lower = (i - kK > 0) ? (i - kK) : 0;

  for (int t = tb; t < te; ++t) {
    const int j = i - kK + t;
    if (j < 0 || j >= kS) continue;     // group-uniform
    const int p = start_i + (j - lower);
    const float* Vr = V + (b * kS + j) * kD;
    const float* Rr = R + t * kD;

    float h[16]; float ssum = 0.f, qsum = 0.f;
#pragma unroll
    for (int q = 0; q < 4; ++q) {
      int d = (q << 6) + (l16 << 2);
      float4 v4 = *(const float4*)(Vr + d);
      float4 r4 = *(const float4*)(Rr + d);
      float h0 = ureg[q * 4 + 0] + v4.x + r4.x;
      float h1 = ureg[q * 4 + 1] + v4.y + r4.y;
      float h2 = ureg[q * 4 + 2] + v4.z + r4.z;
      float h3 = ureg[q * 4 + 3] + v4.w + r4.w;
      h[q * 4 + 0] = h0; h[q * 4 + 1] = h1; h[q * 4 + 2] = h2; h[q * 4 + 3] = h3;
      ssum += h0 + h1 + h2 + h3;
      qsum += h0 * h0 + h1 * h1 + h2 * h2 + h3 * h3;
    }
#pragma unroll
    for (int off = 8; off > 0; off >>= 1) {
      ssum += __shfl_xor(ssum, off);
      qsum += __shfl_xor(qsum, off);
    }
    const float mu = ssum * (1.0f / kD);
    const float var = qsum * (1.0f / kD) - mu * mu;
    const float rs = rsqrtf(var + 1e-5f);
    float dot = 0.f;
#pragma unroll
    for (int q = 0; q < 4; ++q) {
      float y0 = (h[q * 4 + 0] - mu) * rs * Gp[q].x + Bp[q].x;
      float y1 = (h[q * 4 + 1] - mu) * rs * Gp[q].y + Bp[q].y;
      float y2 = (h[q * 4 + 2] - mu) * rs * Gp[q].z + Bp[q].z;
      float y3 = (h[q * 4 + 3] - mu) * rs * Gp[q].w + Bp[q].w;
      y0 = y0 > 0.f ? y0 : (__expf(y0) - 1.0f);   // elu (alpha=1)
      y1 = y1 > 0.f ? y1 : (__expf(y1) - 1.0f);
      y2 = y2 > 0.f ? y2 : (__expf(y2) - 1.0f);
      y3 = y3 > 0.f ? y3 : (__expf(y3) - 1.0f);
      dot += y0 * Wp[q].x + y1 * Wp[q].y + y2 * Wp[q].z + y3 * Wp[q].w;
    }
#pragma unroll
    for (int off = 8; off > 0; off >>= 1) dot += __shfl_xor(dot, off);

    if (l16 == 0) {
      out[b * kNPair + p] = dot + bias2;
      if (b == 0) {
        float* po = out + kB * kNPair;  // positions read back as f32
        po[2 * p + 0] = (float)(i + 1);
        po[2 * p + 1] = (float)(j + 1);
      }
    }
  }
}

// ---------------------------------------------------------------------------
extern "C" void kernel_launch(void* const* d_in, const int* in_sizes, int n_in,
                              void* d_out, int out_size, void* d_ws, size_t ws_size,
                              hipStream_t stream) {
  (void)in_sizes; (void)n_in; (void)ws_size; (void)out_size;
  const float* H       = (const float*)d_in[0];  // [32,128,256]
  const float* pos_emb = (const float*)d_in[1];  // [17,64]
  const float* W1      = (const float*)d_in[2];  // [256,576]
  const float* b1      = (const float*)d_in[3];  // [256]
  const float* ln_g    = (const float*)d_in[4];  // [256]
  const float* ln_b    = (const float*)d_in[5];  // [256]
  const float* W2      = (const float*)d_in[6];  // [1,256]
  const float* b2      = (const float*)d_in[7];  // [1]
  float* out = (float*)d_out;

  float* U  = (float*)d_ws;            // [4096][256] f32
  float* V  = U + kRows * kD;          // [4096][256] f32
  float* Rg = V + kRows * kD;          // [17][256]   f32

  gemm_uv<<<513, 256, 0, stream>>>(H, W1, pos_emb, b1, U, V, Rg);
  pair_score<<<512, 512, 0, stream>>>(U, V, Rg, ln_g, ln_b, W2, b2, out);
}

// Round 9
// 43.030 us; speedup vs baseline: 1.3528x; 1.2278x over previous
//
#include <hip/hip_runtime.h>
#include <math.h>

// Problem constants (fixed by setup_inputs)
constexpr int kB = 32;         // batch
constexpr int kS = 128;        // seq len
constexpr int kD = 256;        // hidden
constexpr int kK = 8;          // window
constexpr int kNPair = 2104;   // pairs with |j-i|<=8
constexpr int kInDim = 2 * kD + 64;  // 576
constexpr int kRows = kB * kS;       // 4096

typedef __attribute__((ext_vector_type(8))) short short8;   // 8 bf16 (4 VGPRs)
typedef __attribute__((ext_vector_type(4))) float f32x4;    // MFMA C/D frag

// f32 -> bf16, round-to-nearest-even
__device__ inline ushort f2b(float f) {
  union { float f; uint u; } v; v.f = f;
  uint r = v.u + 0x7FFF + ((v.u >> 16) & 1);
  return (ushort)(r >> 16);
}

// ---------------------------------------------------------------------------
// Kernel AB (fused): blocks 0..511 do the bf16-MFMA GEMM
//   C[4096][512] = H[4096][256] x Wcat[512][256]^T   (U = cols 0:256, V = rest)
// block 512 computes R[t][d] = sum_u (128-|u-8|)*exp(-(t-u)^2)*(pos_emb[u].W1c[d]) + b1[d]
// EPILOGUE CHANGE vs R3: C-store goes through a per-wave LDS transpose so each
// store instruction writes 16 complete 64B lines (was: 64 scattered 4B writes).
// ---------------------------------------------------------------------------
__global__ __launch_bounds__(256) void gemm_uv_r(
    const float* __restrict__ H, const float* __restrict__ W1,
    const float* __restrict__ pos_emb, const float* __restrict__ b1,
    float* __restrict__ U, float* __restrict__ V, float* __restrict__ R) {
  __shared__ ushort As[64 * 256];   // 32 KB
  __shared__ ushort Bs[64 * 256];   // 32 KB
  __shared__ float sT[4][16 * 20];  // 5 KB per-wave transpose scratch
  const int tid = threadIdx.x;

  if (blockIdx.x == 512) {
    // ---- build_R (one block) ----
    float* pe = (float*)As;  // 17*64 floats, reuse LDS
    for (int idx = tid; idx < 17 * 64; idx += 256) pe[idx] = pos_emb[idx];
    __syncthreads();
    const int d = tid;
    float w[64];
    const float* wr = W1 + d * kInDim + 2 * kD;
#pragma unroll
    for (int q = 0; q < 16; ++q) {
      float4 t4 = *(const float4*)(wr + q * 4);
      w[q * 4 + 0] = t4.x; w[q * 4 + 1] = t4.y;
      w[q * 4 + 2] = t4.z; w[q * 4 + 3] = t4.w;
    }
    float acc[17];
#pragma unroll
    for (int t = 0; t < 17; ++t) acc[t] = 0.f;
    for (int u = 0; u < 17; ++u) {
      float m = 0.f;
#pragma unroll
      for (int p = 0; p < 64; ++p) m += pe[u * 64 + p] * w[p];
      int au = u - kK; if (au < 0) au = -au;
      m *= (float)(kS - au);
#pragma unroll
      for (int t = 0; t < 17; ++t) {
        int dd = t - u;
        acc[t] += expf((float)(-(dd * dd))) * m;
      }
    }
#pragma unroll
    for (int t = 0; t < 17; ++t) R[t * kD + d] = acc[t] + b1[d];
    return;
  }

  // ---- GEMM ----
  const int mt = blockIdx.x & 63;       // M tile (64 rows of H)
  const int nt = blockIdx.x >> 6;       // N tile (64 output cols of 512)
  const int m0 = mt * 64;
  const int side = (nt >= 4) ? kD : 0;  // U-half vs V-half of W1 rows
  const int wbase = (nt & 3) * 64;      // W1 row base within the 256

  // f32 global -> bf16 LDS, XOR-swizzled so ds_read_b128 column slices are ~2-way
#pragma unroll
  for (int l = 0; l < 16; ++l) {
    int c = tid + l * 256;       // 0..4095 float4-chunks
    int row = c >> 6;            // 0..63
    int kq = (c & 63) << 2;      // element offset 0..252
    int sw = (row << 8) + (kq ^ ((row & 7) << 3));
    float4 a4 = *(const float4*)(H + (m0 + row) * kD + kq);
    ushort4 au; au.x = f2b(a4.x); au.y = f2b(a4.y); au.z = f2b(a4.z); au.w = f2b(a4.w);
    *(ushort4*)(As + sw) = au;
    float4 b4 = *(const float4*)(W1 + (wbase + row) * kInDim + side + kq);
    ushort4 bu; bu.x = f2b(b4.x); bu.y = f2b(b4.y); bu.z = f2b(b4.z); bu.w = f2b(b4.w);
    *(ushort4*)(Bs + sw) = bu;
  }
  __syncthreads();

  const int lane = tid & 63;
  const int w = tid >> 6;            // wave 0..3
  const int wm = (w & 1) * 32;
  const int wn = (w >> 1) * 32;
  const int lr = lane & 15;
  const int lk = (lane >> 4) * 8;

  f32x4 acc[2][2] = {{{0.f,0.f,0.f,0.f},{0.f,0.f,0.f,0.f}},
                     {{0.f,0.f,0.f,0.f},{0.f,0.f,0.f,0.f}}};
#pragma unroll
  for (int kk = 0; kk < 8; ++kk) {
    const int k0 = kk * 32 + lk;
    short8 a[2], b[2];
#pragma unroll
    for (int mf = 0; mf < 2; ++mf) {
      int ra = wm + mf * 16 + lr;
      a[mf] = *(const short8*)(const void*)(As + (ra << 8) + (k0 ^ ((ra & 7) << 3)));
      int rb = wn + mf * 16 + lr;
      b[mf] = *(const short8*)(const void*)(Bs + (rb << 8) + (k0 ^ ((rb & 7) << 3)));
    }
#pragma unroll
    for (int mf = 0; mf < 2; ++mf)
#pragma unroll
      for (int nf = 0; nf < 2; ++nf)
        acc[mf][nf] = __builtin_amdgcn_mfma_f32_16x16x32_bf16(a[mf], b[nf], acc[mf][nf], 0, 0, 0);
  }

  // ---- coalesced C-store via per-wave LDS transpose ----
  // Frag layout: value acc[mf][nf][r] = C(row (lane>>4)*4+r, col lane&15) of
  // its 16x16 tile. Write tile to sT (row stride 20 -> 2-way banks, free),
  // wave-internal fence, read back row-major float4, store 1KB/instr.
  float* tw = &sT[w][0];
  const int wrow = (lane >> 4) * 4;   // local row base for writes
  const int c16 = lane & 15;          // local col for writes
  const int rrow = lane >> 2;         // local row for reads (0..15)
  const int rcol = (lane & 3) * 4;    // local col chunk for reads
#pragma unroll
  for (int mf = 0; mf < 2; ++mf)
#pragma unroll
    for (int nf = 0; nf < 2; ++nf) {
#pragma unroll
      for (int r = 0; r < 4; ++r)
        tw[(wrow + r) * 20 + c16] = acc[mf][nf][r];
      asm volatile("s_waitcnt lgkmcnt(0)" ::: "memory");   // writes visible (same wave)
      float4 v4 = *(const float4*)&tw[rrow * 20 + rcol];
      const int colbase = nt * 64 + wn + nf * 16;          // 16-aligned
      const int rowg = m0 + wm + mf * 16 + rrow;
      if (colbase < kD)
        *(float4*)(U + rowg * kD + colbase + rcol) = v4;
      else
        *(float4*)(V + rowg * kD + (colbase - kD) + rcol) = v4;
      asm volatile("s_waitcnt lgkmcnt(0)" ::: "memory");   // reads done before overwrite
    }
}

// ---------------------------------------------------------------------------
// Kernel C: one 16-lane group per pair (4 pairs/wave).
// Lane owns 16 elements at d = q*64 + l16*4 (q=0..3) -> coalesced 256B/inst.
// Reductions are 4-step __shfl_xor (8,4,2,1). ELU via hardware __expf.
// ---------------------------------------------------------------------------
__global__ __launch_bounds__(256) void pair_score2(
    const float* __restrict__ U, const float* __restrict__ V,
    const float* __restrict__ R,
    const float* __restrict__ ln_g, const float* __restrict__ ln_b,
    const float* __restrict__ W2, const float* __restrict__ b2,
    float* __restrict__ out) {
  const int tid = threadIdx.x;
  const int l16 = tid & 15;
  const int grp = (blockIdx.x * 256 + tid) >> 4;   // 16-lane group id
  const int t = grp % 17;                          // rel + 8
  const int bi = grp / 17;
  const int i = bi & (kS - 1);
  const int b = bi >> 7;                           // 0..31 by construction
  const int j = i - kK + t;
  const bool valid = (j >= 0) && (j < kS);
  const int jc = valid ? j : 0;

  // closed-form pair index p
  int start_i;
  if (i <= 8)        start_i = (i * i + 17 * i) / 2;
  else if (i <= 120) start_i = 100 + (i - 8) * 17;
  else { int m = i - 120; start_i = 2004 + 16 * m - (m * (m - 1)) / 2; }
  const int lower = (i - kK > 0) ? (i - kK) : 0;
  const int p = start_i + (j - lower);

  const float* Urow = U + (b * kS + i) * kD;
  const float* Vrow = V + (b * kS + jc) * kD;
  const float* Rrow = R + t * kD;

  float h[16];
  float s = 0.f, qs = 0.f;
#pragma unroll
  for (int q = 0; q < 4; ++q) {
    const int d = q * 64 + l16 * 4;
    float4 u4 = *(const float4*)(Urow + d);
    float4 v4 = *(const float4*)(Vrow + d);
    float4 r4 = *(const float4*)(Rrow + d);
    float h0 = u4.x + v4.x + r4.x;
    float h1 = u4.y + v4.y + r4.y;
    float h2 = u4.z + v4.z + r4.z;
    float h3 = u4.w + v4.w + r4.w;
    h[q * 4 + 0] = h0; h[q * 4 + 1] = h1; h[q * 4 + 2] = h2; h[q * 4 + 3] = h3;
    s += h0 + h1 + h2 + h3;
    qs += h0 * h0 + h1 * h1 + h2 * h2 + h3 * h3;
  }
#pragma unroll
  for (int off = 8; off > 0; off >>= 1) {
    s  += __shfl_xor(s, off);
    qs += __shfl_xor(qs, off);
  }
  const float mu = s * (1.0f / kD);
  const float var = qs * (1.0f / kD) - mu * mu;
  const float rs = rsqrtf(var + 1e-5f);

  float dot = 0.f;
#pragma unroll
  for (int q = 0; q < 4; ++q) {
    const int d = q * 64 + l16 * 4;
    float4 g4  = *(const float4*)(ln_g + d);
    float4 be4 = *(const float4*)(ln_b + d);
    float4 w4  = *(const float4*)(W2 + d);
    float y0 = (h[q * 4 + 0] - mu) * rs * g4.x + be4.x;
    float y1 = (h[q * 4 + 1] - mu) * rs * g4.y + be4.y;
    float y2 = (h[q * 4 + 2] - mu) * rs * g4.z + be4.z;
    float y3 = (h[q * 4 + 3] - mu) * rs * g4.w + be4.w;
    y0 = y0 > 0.f ? y0 : (__expf(y0) - 1.0f);   // elu (alpha=1), hw exp
    y1 = y1 > 0.f ? y1 : (__expf(y1) - 1.0f);
    y2 = y2 > 0.f ? y2 : (__expf(y2) - 1.0f);
    y3 = y3 > 0.f ? y3 : (__expf(y3) - 1.0f);
    dot += y0 * w4.x + y1 * w4.y + y2 * w4.z + y3 * w4.w;
  }
#pragma unroll
  for (int off = 8; off > 0; off >>= 1) dot += __shfl_xor(dot, off);

  if (l16 == 0 && valid) {
    out[b * kNPair + p] = dot + b2[0];
    if (b == 0) {
      float* posout = out + kB * kNPair;   // positions read back as f32
      posout[p * 2 + 0] = (float)(i + 1);
      posout[p * 2 + 1] = (float)(j + 1);
    }
  }
}

// ---------------------------------------------------------------------------
extern "C" void kernel_launch(void* const* d_in, const int* in_sizes, int n_in,
                              void* d_out, int out_size, void* d_ws, size_t ws_size,
                              hipStream_t stream) {
  (void)in_sizes; (void)n_in; (void)ws_size; (void)out_size;
  const float* H       = (const float*)d_in[0];  // [32,128,256]
  const float* pos_emb = (const float*)d_in[1];  // [17,64]
  const float* W1      = (const float*)d_in[2];  // [256,576]
  const float* b1      = (const float*)d_in[3];  // [256]
  const float* ln_g    = (const float*)d_in[4];  // [256]
  const float* ln_b    = (const float*)d_in[5];  // [256]
  const float* W2      = (const float*)d_in[6];  // [1,256]
  const float* b2      = (const float*)d_in[7];  // [1]
  float* out = (float*)d_out;

  float* U = (float*)d_ws;            // [4096,256]  4 MB
  float* V = U + kRows * kD;          // [4096,256]  4 MB
  float* R = V + kRows * kD;          // [17,256]

  gemm_uv_r<<<513, 256, 0, stream>>>(H, W1, pos_emb, b1, U, V, R);
  const int n_groups = kB * kS * 17;  // 69632 pair-slots, 16 per block
  pair_score2<<<n_groups / 16, 256, 0, stream>>>(U, V, R, ln_g, ln_b, W2, b2, out);
}